// Round 1
// baseline (220.858 us; speedup 1.0000x reference)
//
#include <hip/hip_runtime.h>

// y = (spikes @ V) @ U^T
// spikes: [4096, 16384] f32, V: [16384, 32] f32, U: [16384, 32] f32
// out y: [4096, 16384] f32 (268 MB). Mask inputs are unused (dead in reference).

#define B_DIM 4096
#define NPRE  16384
#define NPOST 16384
#define RDIM  32

// ---- phase A: z partials -------------------------------------------------
#define NC      8       // K-split chunks
#define CHUNK   (NPRE / NC)   // 2048
#define TI      128     // i per staged tile
#define ROWS_A  64      // b-rows per block
#define PADW    (TI + 1)      // 129, conflict-free lane-strided reads
#define REDSTR  2112    // 64*33 per-wave partial stride (padded)

__global__ __launch_bounds__(512, 2) void zpart_kernel(
    const float* __restrict__ spikes, const float* __restrict__ V,
    float* __restrict__ part)
{
    __shared__ float smem[8 * REDSTR];   // 67.6 KB (tile aliases front: 64*129=8256 floats)

    const int tid  = threadIdx.x;
    const int wid  = tid >> 6;           // 0..7
    const int lane = tid & 63;
    const int c    = blockIdx.x;         // chunk index
    const int brow = blockIdx.y * ROWS_A;
    const int ibase0 = c * CHUNK;

    float acc[RDIM];
    #pragma unroll
    for (int r = 0; r < RDIM; ++r) acc[r] = 0.f;

    const int srow = tid >> 5;           // 0..15 (16 rows per staging pass)
    const int scol = (tid & 31) * 4;     // 0..124

    // wave-uniform i-offset, forced into an SGPR so V loads become s_load
    const int i0 = __builtin_amdgcn_readfirstlane(wid * 16);

    for (int t = 0; t < CHUNK / TI; ++t) {
        const int ibase = ibase0 + t * TI;
        __syncthreads();                 // protect tile from previous round's readers
        #pragma unroll
        for (int p = 0; p < 4; ++p) {
            const int row = p * 16 + srow;
            const float4 v4 = *reinterpret_cast<const float4*>(
                &spikes[(size_t)(brow + row) * NPRE + ibase + scol]);
            float* dst = &smem[row * PADW + scol];
            dst[0] = v4.x; dst[1] = v4.y; dst[2] = v4.z; dst[3] = v4.w;
        }
        __syncthreads();
        #pragma unroll
        for (int ii = 0; ii < 16; ++ii) {
            const float s = smem[lane * PADW + i0 + ii];
            const float* vr = &V[(size_t)(ibase + i0 + ii) * RDIM];
            #pragma unroll
            for (int r = 0; r < RDIM; ++r) acc[r] += s * vr[r];
        }
    }

    __syncthreads();                     // tile no longer needed; reuse smem for reduction
    #pragma unroll
    for (int r = 0; r < RDIM; ++r) smem[wid * REDSTR + lane * 33 + r] = acc[r];
    __syncthreads();

    // reduce 8 wave-partials; each thread produces 4 consecutive (b,r) outputs
    {
        const int p  = tid * 4;          // 0..2044 over 64*32 outputs
        const int b  = p >> 5;
        const int r0 = p & 31;
        float sx = 0.f, sy = 0.f, sz = 0.f, sw = 0.f;
        #pragma unroll
        for (int w = 0; w < 8; ++w) {
            const float* src = &smem[w * REDSTR + b * 33 + r0];
            sx += src[0]; sy += src[1]; sz += src[2]; sw += src[3];
        }
        float4 s4; s4.x = sx; s4.y = sy; s4.z = sz; s4.w = sw;
        *reinterpret_cast<float4*>(
            &part[(size_t)c * (B_DIM * RDIM) + (size_t)(brow + b) * RDIM + r0]) = s4;
    }
}

// ---- z reduction: z[b][r] = sum_c part[c][b][r] --------------------------
__global__ void zreduce_kernel(const float* __restrict__ part, float* __restrict__ z)
{
    const int idx = (blockIdx.x * blockDim.x + threadIdx.x) * 4;  // over 131072 floats
    float sx = 0.f, sy = 0.f, sz = 0.f, sw = 0.f;
    #pragma unroll
    for (int c = 0; c < NC; ++c) {
        const float4 p = *reinterpret_cast<const float4*>(&part[(size_t)c * (B_DIM * RDIM) + idx]);
        sx += p.x; sy += p.y; sz += p.z; sw += p.w;
    }
    float4 s4; s4.x = sx; s4.y = sy; s4.z = sz; s4.w = sw;
    *reinterpret_cast<float4*>(&z[idx]) = s4;
}

// ---- phase B: y[b][j] = sum_r z[b][r] * U[j][r] --------------------------
#define TJ 256
#define TB 64

__global__ __launch_bounds__(256) void ykernel(
    const float* __restrict__ z, const float* __restrict__ U,
    float* __restrict__ y)
{
    const int j  = blockIdx.x * TJ + threadIdx.x;
    const int b0 = blockIdx.y * TB;

    float u[RDIM];
    #pragma unroll
    for (int q = 0; q < 8; ++q) {
        const float4 v = *reinterpret_cast<const float4*>(&U[(size_t)j * RDIM + q * 4]);
        u[q * 4 + 0] = v.x; u[q * 4 + 1] = v.y; u[q * 4 + 2] = v.z; u[q * 4 + 3] = v.w;
    }

    for (int bb = 0; bb < TB; ++bb) {
        const float* zr = &z[(size_t)(b0 + bb) * RDIM];   // wave-uniform -> s_load
        float a0 = 0.f, a1 = 0.f, a2 = 0.f, a3 = 0.f;
        #pragma unroll
        for (int r = 0; r < RDIM; r += 4) {
            a0 += zr[r + 0] * u[r + 0];
            a1 += zr[r + 1] * u[r + 1];
            a2 += zr[r + 2] * u[r + 2];
            a3 += zr[r + 3] * u[r + 3];
        }
        y[(size_t)(b0 + bb) * NPOST + j] = (a0 + a1) + (a2 + a3);
    }
}

extern "C" void kernel_launch(void* const* d_in, const int* in_sizes, int n_in,
                              void* d_out, int out_size, void* d_ws, size_t ws_size,
                              hipStream_t stream)
{
    const float* spikes = (const float*)d_in[0];   // [4096, 16384]
    const float* U      = (const float*)d_in[1];   // [16384, 32]
    const float* V      = (const float*)d_in[2];   // [16384, 32]
    float* y    = (float*)d_out;
    float* part = (float*)d_out;                   // first 4 MB of d_out, consumed before y overwrites
    float* z    = (float*)d_ws;                    // 512 KB scratch

    zpart_kernel<<<dim3(NC, B_DIM / ROWS_A), 512, 0, stream>>>(spikes, V, part);
    zreduce_kernel<<<dim3((B_DIM * RDIM / 4) / 256), 256, 0, stream>>>(part, z);
    ykernel<<<dim3(NPOST / TJ, B_DIM / TB), 256, 0, stream>>>(z, U, y);
}